// Round 1
// baseline (2453.554 us; speedup 1.0000x reference)
//
#include <hip/hip_runtime.h>
#include <math.h>

#define BB 4
#define SS 2048
#define DD 1024
#define HH 16
#define DHH 64

// ---------------------------------------------------------------------------
// GEMM: C = X (MxK) @ W^T, W stored row-major (N x K) (torch Linear weight).
// 64x64 output tile per block, 256 threads, 4x4 micro-tile per thread.
// LDS tiles stored K-major-transposed: Xs[kk][row] so compute reads are
// float4 (ds_read_b128), 2-way conflicts max.
// MODE 0: plain row-major C (M x N)
// MODE 1: head-split write C[((b*H+h)*S+s)*DH+dh] with m=b*S+s, n=h*DH+dh
// ---------------------------------------------------------------------------
template <int MODE>
__global__ __launch_bounds__(256)
void gemm_xwt(const float* __restrict__ X, const float* __restrict__ W,
              float* __restrict__ C)
{
    constexpr int K = DD;
    constexpr int N = DD;
    __shared__ float Xs[16][68];
    __shared__ float Ws[16][68];

    const int m0 = blockIdx.y * 64;
    const int n0 = blockIdx.x * 64;
    const int t  = threadIdx.x;
    const int tx = t & 15;        // 0..15 -> n micro
    const int ty = t >> 4;        // 0..15 -> m micro
    const int lr = t >> 2;        // 0..63 loader row
    const int lc = (t & 3) * 4;   // 0,4,8,12 loader k-offset

    const float* xp = X + (size_t)(m0 + lr) * K + lc;
    const float* wp = W + (size_t)(n0 + lr) * K + lc;

    float acc[4][4] = {};

    for (int k0 = 0; k0 < K; k0 += 16) {
        const float4 xv = *reinterpret_cast<const float4*>(xp + k0);
        const float4 wv = *reinterpret_cast<const float4*>(wp + k0);
        __syncthreads();
        Xs[lc + 0][lr] = xv.x; Xs[lc + 1][lr] = xv.y;
        Xs[lc + 2][lr] = xv.z; Xs[lc + 3][lr] = xv.w;
        Ws[lc + 0][lr] = wv.x; Ws[lc + 1][lr] = wv.y;
        Ws[lc + 2][lr] = wv.z; Ws[lc + 3][lr] = wv.w;
        __syncthreads();
        #pragma unroll
        for (int kk = 0; kk < 16; ++kk) {
            const float4 xr4 = *reinterpret_cast<const float4*>(&Xs[kk][ty * 4]);
            const float4 wr4 = *reinterpret_cast<const float4*>(&Ws[kk][tx * 4]);
            const float xr[4] = {xr4.x, xr4.y, xr4.z, xr4.w};
            const float wr[4] = {wr4.x, wr4.y, wr4.z, wr4.w};
            #pragma unroll
            for (int i = 0; i < 4; ++i)
                #pragma unroll
                for (int j = 0; j < 4; ++j)
                    acc[i][j] += xr[i] * wr[j];
        }
    }

    #pragma unroll
    for (int i = 0; i < 4; ++i) {
        const int m = m0 + ty * 4 + i;
        const int n = n0 + tx * 4;   // j contiguous, same head for all 4 j
        float4 ov;
        ov.x = acc[i][0]; ov.y = acc[i][1]; ov.z = acc[i][2]; ov.w = acc[i][3];
        if (MODE == 0) {
            *reinterpret_cast<float4*>(&C[(size_t)m * N + n]) = ov;
        } else {
            const int b = m >> 11;        // /S
            const int s = m & (SS - 1);
            const int h = n >> 6;         // /DH
            const int dh = n & (DHH - 1);
            *reinterpret_cast<float4*>(
                &C[(((size_t)b * HH + h) * SS + s) * DHH + dh]) = ov;
        }
    }
}

// ---------------------------------------------------------------------------
// Flash attention, fp32. One thread per query row (256 rows/block).
// K/V tiles (64 x 64) staged in LDS, broadcast float4 reads.
// Online softmax in 16-column subtiles. KV tiles fully past valid_len are
// skipped (exp(-1e6 - m) == 0 in fp32, identical to reference masking).
// Output written in (B, S, D) concat-head layout, already /l normalized.
// ---------------------------------------------------------------------------
__global__ __launch_bounds__(256)
void flash_attn(const float* __restrict__ Qp, const float* __restrict__ Kp,
                const float* __restrict__ Vp, const int* __restrict__ vlens,
                float* __restrict__ AO)
{
    __shared__ float Ks[64][68];
    __shared__ float Vs[64][68];

    const int bh  = blockIdx.y;          // 0..63
    const int b   = bh >> 4;             // /H
    const int h   = bh & (HH - 1);
    const int t   = threadIdx.x;
    const int row = blockIdx.x * 256 + t;
    const int vlen = vlens[b];

    // load my q row (strided across lanes; once per block, amortized)
    float q[64];
    const float* qbase = Qp + ((size_t)bh * SS + row) * DHH;
    #pragma unroll
    for (int d4 = 0; d4 < 16; ++d4) {
        const float4 v = *reinterpret_cast<const float4*>(qbase + d4 * 4);
        q[d4 * 4 + 0] = v.x; q[d4 * 4 + 1] = v.y;
        q[d4 * 4 + 2] = v.z; q[d4 * 4 + 3] = v.w;
    }

    float m = -1e30f;
    float l = 0.f;
    float o[64];
    #pragma unroll
    for (int d = 0; d < 64; ++d) o[d] = 0.f;

    const float* kbase = Kp + (size_t)bh * SS * DHH;
    const float* vbase = Vp + (size_t)bh * SS * DHH;

    const int ntiles = (vlen + 63) >> 6;
    for (int tile = 0; tile < ntiles; ++tile) {
        const int c0 = tile * 64;
        __syncthreads();
        #pragma unroll
        for (int i = 0; i < 4; ++i) {
            const int f  = t + i * 256;        // 0..1023 float4 slots
            const int r  = f >> 4;
            const int c4 = (f & 15) * 4;
            *reinterpret_cast<float4*>(&Ks[r][c4]) =
                *reinterpret_cast<const float4*>(kbase + (size_t)(c0 + r) * DHH + c4);
            *reinterpret_cast<float4*>(&Vs[r][c4]) =
                *reinterpret_cast<const float4*>(vbase + (size_t)(c0 + r) * DHH + c4);
        }
        __syncthreads();

        const int cmax = vlen - c0;   // >=1; cols >= cmax are masked
        for (int cs = 0; cs < 64; cs += 16) {
            float sc[16];
            float smax = -1e30f;
            #pragma unroll
            for (int cc = 0; cc < 16; ++cc) {
                const int c = cs + cc;
                float a = 0.f;
                #pragma unroll
                for (int d4 = 0; d4 < 16; ++d4) {
                    const float4 kv = *reinterpret_cast<const float4*>(&Ks[c][d4 * 4]);
                    a += q[d4 * 4 + 0] * kv.x;
                    a += q[d4 * 4 + 1] * kv.y;
                    a += q[d4 * 4 + 2] * kv.z;
                    a += q[d4 * 4 + 3] * kv.w;
                }
                a = (c < cmax) ? a * 0.125f : -1e6f;
                sc[cc] = a;
                smax = fmaxf(smax, a);
            }
            const float mn   = fmaxf(m, smax);
            const float corr = __expf(m - mn);   // first subtile: exp(-huge)=0
            l *= corr;
            #pragma unroll
            for (int d = 0; d < 64; ++d) o[d] *= corr;
            #pragma unroll
            for (int cc = 0; cc < 16; ++cc) {
                sc[cc] = __expf(sc[cc] - mn);
                l += sc[cc];
            }
            m = mn;
            #pragma unroll
            for (int cc = 0; cc < 16; ++cc) {
                const float pc = sc[cc];
                const int c = cs + cc;
                #pragma unroll
                for (int d4 = 0; d4 < 16; ++d4) {
                    const float4 vv = *reinterpret_cast<const float4*>(&Vs[c][d4 * 4]);
                    o[d4 * 4 + 0] += pc * vv.x;
                    o[d4 * 4 + 1] += pc * vv.y;
                    o[d4 * 4 + 2] += pc * vv.z;
                    o[d4 * 4 + 3] += pc * vv.w;
                }
            }
        }
    }

    const float inv = 1.f / l;
    float* obase = AO + ((size_t)b * SS + row) * DD + h * DHH;
    #pragma unroll
    for (int d4 = 0; d4 < 16; ++d4) {
        float4 ov;
        ov.x = o[d4 * 4 + 0] * inv; ov.y = o[d4 * 4 + 1] * inv;
        ov.z = o[d4 * 4 + 2] * inv; ov.w = o[d4 * 4 + 3] * inv;
        *reinterpret_cast<float4*>(obase + d4 * 4) = ov;
    }
}

extern "C" void kernel_launch(void* const* d_in, const int* in_sizes, int n_in,
                              void* d_out, int out_size, void* d_ws, size_t ws_size,
                              hipStream_t stream) {
    const float* queries = (const float*)d_in[0];
    const float* keys    = (const float*)d_in[1];
    const float* values  = (const float*)d_in[2];
    const int*   vlens   = (const int*)d_in[3];
    const float* Wq      = (const float*)d_in[4];
    const float* Wk      = (const float*)d_in[5];
    const float* Wv      = (const float*)d_in[6];
    const float* Wo      = (const float*)d_in[7];
    float* out = (float*)d_out;

    float* ws = (float*)d_ws;
    const size_t SZ = (size_t)BB * HH * SS * DHH;   // 8,388,608 floats
    float* Qp = ws;
    float* Kp = ws + SZ;
    float* Vp = ws + 2 * SZ;
    float* AO = ws + 3 * SZ;

    const dim3 gg(DD / 64, (BB * SS) / 64, 1);   // (16, 128)
    const dim3 bb(256);

    gemm_xwt<1><<<gg, bb, 0, stream>>>(queries, Wq, Qp);
    gemm_xwt<1><<<gg, bb, 0, stream>>>(keys,    Wk, Kp);
    gemm_xwt<1><<<gg, bb, 0, stream>>>(values,  Wv, Vp);

    flash_attn<<<dim3(SS / 256, BB * HH), bb, 0, stream>>>(Qp, Kp, Vp, vlens, AO);

    gemm_xwt<0><<<gg, bb, 0, stream>>>(AO, Wo, out);
}

// Round 2
// 436.794 us; speedup vs baseline: 5.6172x; 5.6172x over previous
//
#include <hip/hip_runtime.h>
#include <math.h>

#define BB 4
#define SS 2048
#define DD 1024
#define HH 16
#define DHH 64
#define NBH 64

typedef __attribute__((ext_vector_type(8))) short bf16x8;
typedef __attribute__((ext_vector_type(8))) unsigned short ushort8;
typedef __attribute__((ext_vector_type(4))) float f32x4;
typedef unsigned short u16;

__device__ inline u16 f2bf(float x) {
    union { float f; unsigned u; } v; v.f = x;
    unsigned r = v.u + 0x7fffu + ((v.u >> 16) & 1u);   // RNE
    return (u16)(r >> 16);
}

__device__ inline void gload16(const u16* g, u16* l) {
    __builtin_amdgcn_global_load_lds(
        (const __attribute__((address_space(1))) unsigned int*)(const void*)g,
        (__attribute__((address_space(3))) unsigned int*)(void*)l, 16, 0, 0);
}

// ---------------------------------------------------------------------------
// fp32 -> bf16 conversion (vectorized, 8 elems/thread)
// ---------------------------------------------------------------------------
__global__ __launch_bounds__(256)
void cvt_qkv(const float* __restrict__ q, const float* __restrict__ k,
             const float* __restrict__ v,
             u16* __restrict__ oq, u16* __restrict__ ok, u16* __restrict__ ov)
{
    const float* s; u16* d;
    if (blockIdx.y == 0) { s = q; d = oq; }
    else if (blockIdx.y == 1) { s = k; d = ok; }
    else { s = v; d = ov; }
    const size_t i = ((size_t)blockIdx.x * 256 + threadIdx.x) * 8;
    const float4 a = *(const float4*)(s + i);
    const float4 c = *(const float4*)(s + i + 4);
    ushort8 r;
    r[0] = f2bf(a.x); r[1] = f2bf(a.y); r[2] = f2bf(a.z); r[3] = f2bf(a.w);
    r[4] = f2bf(c.x); r[5] = f2bf(c.y); r[6] = f2bf(c.z); r[7] = f2bf(c.w);
    *(ushort8*)(d + i) = r;
}

__global__ __launch_bounds__(256)
void cvt_w(const float* __restrict__ a, const float* __restrict__ b,
           const float* __restrict__ c, const float* __restrict__ e,
           u16* __restrict__ oa, u16* __restrict__ ob,
           u16* __restrict__ oc, u16* __restrict__ oe)
{
    const float* s; u16* d;
    if (blockIdx.y == 0) { s = a; d = oa; }
    else if (blockIdx.y == 1) { s = b; d = ob; }
    else if (blockIdx.y == 2) { s = c; d = oc; }
    else { s = e; d = oe; }
    const size_t i = ((size_t)blockIdx.x * 256 + threadIdx.x) * 8;
    const float4 x = *(const float4*)(s + i);
    const float4 y = *(const float4*)(s + i + 4);
    ushort8 r;
    r[0] = f2bf(x.x); r[1] = f2bf(x.y); r[2] = f2bf(x.z); r[3] = f2bf(x.w);
    r[4] = f2bf(y.x); r[5] = f2bf(y.y); r[6] = f2bf(y.z); r[7] = f2bf(y.w);
    *(ushort8*)(d + i) = r;
}

// ---------------------------------------------------------------------------
// V (BH,S,DH) -> Vt (BH,DH,S) transpose, bf16, LDS tiled
// ---------------------------------------------------------------------------
__global__ __launch_bounds__(256)
void transpose_v(const u16* __restrict__ Vp, u16* __restrict__ Vt)
{
    __shared__ __align__(16) u16 tile[64][72];
    const int t = threadIdx.x;
    const int s0 = blockIdx.x * 64;
    const int bh = blockIdx.y;
    const u16* src = Vp + ((size_t)bh * SS + s0) * DHH;
    const int r = t >> 2, d0 = (t & 3) * 16;
    *(ushort8*)&tile[r][d0]     = *(const ushort8*)(src + r * DHH + d0);
    *(ushort8*)&tile[r][d0 + 8] = *(const ushort8*)(src + r * DHH + d0 + 8);
    __syncthreads();
    const int d = t >> 2, sl = (t & 3) * 16;
    ushort8 o0, o1;
    #pragma unroll
    for (int j = 0; j < 8; ++j) o0[j] = tile[sl + j][d];
    #pragma unroll
    for (int j = 0; j < 8; ++j) o1[j] = tile[sl + 8 + j][d];
    u16* dst = Vt + ((size_t)bh * DHH + d) * SS + s0 + sl;
    *(ushort8*)dst       = o0;
    *(ushort8*)(dst + 8) = o1;
}

// ---------------------------------------------------------------------------
// bf16 NT GEMM: C = A (Mx1024) @ B^T, B row-major (1024x1024), 128x128 tile,
// BK=32, 4 waves (2x2), global_load_lds width-16 staging (m97 structure).
// OUT_MODE 0: fp32 row-major. OUT_MODE 1: bf16 head-split (B,H,S,DH).
// ---------------------------------------------------------------------------
template<int OUT_MODE>
__global__ __launch_bounds__(256)
void gemm_nt(const u16* __restrict__ A, const u16* __restrict__ B,
             void* __restrict__ Cv)
{
    __shared__ __align__(16) u16 As[128 * 32];
    __shared__ __align__(16) u16 Bs[128 * 32];
    const int t = threadIdx.x;
    const int w = t >> 6, l = t & 63;
    const int lm = l & 15, lg = l >> 4;
    const int m0 = blockIdx.y * 128, n0 = blockIdx.x * 128;
    const int wr = w >> 1, wc = w & 1;

    const u16* ga = A + (size_t)(m0 + w * 32 + (l >> 2)) * DD + (l & 3) * 8;
    const u16* gb = B + (size_t)(n0 + w * 32 + (l >> 2)) * DD + (l & 3) * 8;
    u16* lA0 = &As[w * 1024];
    u16* lA1 = &As[w * 1024 + 512];
    u16* lB0 = &Bs[w * 1024];
    u16* lB1 = &Bs[w * 1024 + 512];

    f32x4 acc[4][4];
    #pragma unroll
    for (int i = 0; i < 4; ++i)
        #pragma unroll
        for (int j = 0; j < 4; ++j)
            acc[i][j] = (f32x4){0.f, 0.f, 0.f, 0.f};

    for (int k0 = 0; k0 < DD; k0 += 32) {
        __syncthreads();
        gload16(ga + k0,           lA0);
        gload16(ga + k0 + 16 * DD, lA1);
        gload16(gb + k0,           lB0);
        gload16(gb + k0 + 16 * DD, lB1);
        __syncthreads();
        bf16x8 af[4], bfr[4];
        #pragma unroll
        for (int mi = 0; mi < 4; ++mi)
            af[mi] = *(const bf16x8*)&As[(wr * 64 + mi * 16 + lm) * 32 + lg * 8];
        #pragma unroll
        for (int ni = 0; ni < 4; ++ni)
            bfr[ni] = *(const bf16x8*)&Bs[(wc * 64 + ni * 16 + lm) * 32 + lg * 8];
        #pragma unroll
        for (int mi = 0; mi < 4; ++mi)
            #pragma unroll
            for (int ni = 0; ni < 4; ++ni)
                acc[mi][ni] = __builtin_amdgcn_mfma_f32_16x16x32_bf16(
                    af[mi], bfr[ni], acc[mi][ni], 0, 0, 0);
    }

    #pragma unroll
    for (int mi = 0; mi < 4; ++mi) {
        #pragma unroll
        for (int r = 0; r < 4; ++r) {
            const int m = m0 + wr * 64 + mi * 16 + lg * 4 + r;
            if (OUT_MODE == 0) {
                float* C = (float*)Cv;
                #pragma unroll
                for (int ni = 0; ni < 4; ++ni)
                    C[(size_t)m * DD + n0 + wc * 64 + ni * 16 + lm] = acc[mi][ni][r];
            } else {
                u16* C = (u16*)Cv;
                const int b = m >> 11, s = m & (SS - 1);
                #pragma unroll
                for (int ni = 0; ni < 4; ++ni) {
                    const int n = n0 + wc * 64 + ni * 16 + lm;
                    const int h = n >> 6, dh = n & 63;
                    C[(((size_t)b * HH + h) * SS + s) * DHH + dh] = f2bf(acc[mi][ni][r]);
                }
            }
        }
    }
}

// ---------------------------------------------------------------------------
// MFMA flash attention. 4 independent waves/block, 16 q-rows each, 64-col KV
// tiles. K and Vt fragments straight from global (8 KB tiles are L1-resident,
// shared by the block's waves). Wave-parallel softmax via shfl_xor over the
// 16-lane column groups. P relayout (C/D->A operand) via per-wave LDS buffer.
// KV tiles wholly past valid_len are skipped (== reference -1e6 masking).
// ---------------------------------------------------------------------------
__global__ __launch_bounds__(256)
void flash_mfma(const u16* __restrict__ Qp, const u16* __restrict__ Kp,
                const u16* __restrict__ Vt, const int* __restrict__ vlens,
                u16* __restrict__ AO)
{
    __shared__ __align__(16) u16 P_lds[4][16 * 72];
    const int t = threadIdx.x, w = t >> 6, l = t & 63;
    const int lm = l & 15, lg = l >> 4;
    const int bh = blockIdx.y, b = bh >> 4, h = bh & 15;
    const int vlen = vlens[b];
    const int q0 = blockIdx.x * 64 + w * 16;

    const u16* qb = Qp + ((size_t)bh * SS + q0 + lm) * DHH + lg * 8;
    const bf16x8 qf0 = *(const bf16x8*)qb;
    const bf16x8 qf1 = *(const bf16x8*)(qb + 32);

    f32x4 o[4];
    float m_r[4], l_r[4];
    #pragma unroll
    for (int r = 0; r < 4; ++r) { m_r[r] = -1e30f; l_r[r] = 0.f; }
    #pragma unroll
    for (int df = 0; df < 4; ++df) o[df] = (f32x4){0.f, 0.f, 0.f, 0.f};

    const u16* kb = Kp + (size_t)bh * SS * DHH;
    const u16* vb = Vt + (size_t)bh * DHH * SS;
    u16* pw = &P_lds[w][0];

    const int ntiles = (vlen + 63) >> 6;
    for (int tile = 0; tile < ntiles; ++tile) {
        const int c0 = tile * 64;
        f32x4 s[4];
        #pragma unroll
        for (int cf = 0; cf < 4; ++cf) {
            const u16* kr = kb + (size_t)(c0 + cf * 16 + lm) * DHH + lg * 8;
            const bf16x8 k0v = *(const bf16x8*)kr;
            const bf16x8 k1v = *(const bf16x8*)(kr + 32);
            f32x4 z = (f32x4){0.f, 0.f, 0.f, 0.f};
            z = __builtin_amdgcn_mfma_f32_16x16x32_bf16(qf0, k0v, z, 0, 0, 0);
            z = __builtin_amdgcn_mfma_f32_16x16x32_bf16(qf1, k1v, z, 0, 0, 0);
            s[cf] = z;
        }
        const int rem = vlen - c0;   // >= 1
        #pragma unroll
        for (int cf = 0; cf < 4; ++cf) {
            const bool valid = (cf * 16 + lm) < rem;
            #pragma unroll
            for (int r = 0; r < 4; ++r)
                s[cf][r] = valid ? s[cf][r] * 0.125f : -1e30f;
        }
        float vmax[4];
        #pragma unroll
        for (int r = 0; r < 4; ++r)
            vmax[r] = fmaxf(fmaxf(s[0][r], s[1][r]), fmaxf(s[2][r], s[3][r]));
        #pragma unroll
        for (int d = 1; d < 16; d <<= 1)
            #pragma unroll
            for (int r = 0; r < 4; ++r)
                vmax[r] = fmaxf(vmax[r], __shfl_xor(vmax[r], d));
        float corr[4];
        #pragma unroll
        for (int r = 0; r < 4; ++r) {
            const float mn = fmaxf(m_r[r], vmax[r]);
            corr[r] = __expf(m_r[r] - mn);
            m_r[r] = mn;
        }
        float ps[4] = {0.f, 0.f, 0.f, 0.f};
        #pragma unroll
        for (int cf = 0; cf < 4; ++cf)
            #pragma unroll
            for (int r = 0; r < 4; ++r) {
                const float p = __expf(s[cf][r] - m_r[r]);
                s[cf][r] = p;
                ps[r] += p;
            }
        #pragma unroll
        for (int d = 1; d < 16; d <<= 1)
            #pragma unroll
            for (int r = 0; r < 4; ++r)
                ps[r] += __shfl_xor(ps[r], d);
        #pragma unroll
        for (int r = 0; r < 4; ++r)
            l_r[r] = l_r[r] * corr[r] + ps[r];
        #pragma unroll
        for (int df = 0; df < 4; ++df)
            #pragma unroll
            for (int r = 0; r < 4; ++r)
                o[df][r] *= corr[r];
        // P (C/D layout) -> LDS -> A-operand layout, bf16
        #pragma unroll
        for (int cf = 0; cf < 4; ++cf)
            #pragma unroll
            for (int r = 0; r < 4; ++r)
                pw[(lg * 4 + r) * 72 + cf * 16 + lm] = f2bf(s[cf][r]);
        asm volatile("s_waitcnt lgkmcnt(0)" ::: "memory");
        __builtin_amdgcn_sched_barrier(0);
        const bf16x8 pa0 = *(const bf16x8*)&pw[lm * 72 + lg * 8];
        const bf16x8 pa1 = *(const bf16x8*)&pw[lm * 72 + 32 + lg * 8];
        __builtin_amdgcn_sched_barrier(0);
        #pragma unroll
        for (int df = 0; df < 4; ++df) {
            const u16* vr = vb + (size_t)(df * 16 + lm) * SS + c0 + lg * 8;
            const bf16x8 v0 = *(const bf16x8*)vr;
            const bf16x8 v1 = *(const bf16x8*)(vr + 32);
            o[df] = __builtin_amdgcn_mfma_f32_16x16x32_bf16(pa0, v0, o[df], 0, 0, 0);
            o[df] = __builtin_amdgcn_mfma_f32_16x16x32_bf16(pa1, v1, o[df], 0, 0, 0);
        }
    }
    #pragma unroll
    for (int r = 0; r < 4; ++r) {
        const float inv = 1.f / l_r[r];
        const size_t rowbase = ((size_t)b * SS + q0 + lg * 4 + r) * DD + h * DHH;
        #pragma unroll
        for (int df = 0; df < 4; ++df)
            AO[rowbase + df * 16 + lm] = f2bf(o[df][r] * inv);
    }
}

extern "C" void kernel_launch(void* const* d_in, const int* in_sizes, int n_in,
                              void* d_out, int out_size, void* d_ws, size_t ws_size,
                              hipStream_t stream) {
    const float* queries = (const float*)d_in[0];
    const float* keys    = (const float*)d_in[1];
    const float* values  = (const float*)d_in[2];
    const int*   vlens   = (const int*)d_in[3];
    const float* Wq      = (const float*)d_in[4];
    const float* Wk      = (const float*)d_in[5];
    const float* Wv      = (const float*)d_in[6];
    const float* Wo      = (const float*)d_in[7];

    u16* ws = (u16*)d_ws;
    const size_t NX = (size_t)BB * SS * DD;   // 8,388,608
    const size_t NW = (size_t)DD * DD;        // 1,048,576
    u16* Xq  = ws;
    u16* Xk  = Xq  + NX;
    u16* Xv  = Xk  + NX;
    u16* Wqb = Xv  + NX;
    u16* Wkb = Wqb + NW;
    u16* Wvb = Wkb + NW;
    u16* Wob = Wvb + NW;
    u16* Qp  = Wob + NW;
    u16* Kp  = Qp  + NX;
    u16* Vp  = Kp  + NX;
    u16* Vtb = Vp  + NX;
    u16* AO  = Xq;   // alias: Xq dead after the Q projection

    cvt_qkv<<<dim3(NX / 2048, 3), 256, 0, stream>>>(queries, keys, values, Xq, Xk, Xv);
    cvt_w<<<dim3(NW / 2048, 4), 256, 0, stream>>>(Wq, Wk, Wv, Wo, Wqb, Wkb, Wvb, Wob);

    const dim3 gg(DD / 128, (BB * SS) / 128);   // (8, 64)
    gemm_nt<1><<<gg, 256, 0, stream>>>(Xq, Wqb, Qp);
    gemm_nt<1><<<gg, 256, 0, stream>>>(Xk, Wkb, Kp);
    gemm_nt<1><<<gg, 256, 0, stream>>>(Xv, Wvb, Vp);

    transpose_v<<<dim3(SS / 64, NBH), 256, 0, stream>>>(Vp, Vtb);
    flash_mfma<<<dim3(SS / 64, NBH), 256, 0, stream>>>(Qp, Kp, Vtb, vlens, AO);

    gemm_nt<0><<<gg, 256, 0, stream>>>(AO, Wob, (float*)d_out);
}

// Round 3
// 399.751 us; speedup vs baseline: 6.1377x; 1.0927x over previous
//
#include <hip/hip_runtime.h>
#include <math.h>

#define BB 4
#define SS 2048
#define DD 1024
#define HH 16
#define DHH 64
#define NBH 64

typedef __attribute__((ext_vector_type(8))) short bf16x8;
typedef __attribute__((ext_vector_type(8))) unsigned short ushort8;
typedef __attribute__((ext_vector_type(4))) float f32x4;
typedef unsigned short u16;

__device__ inline u16 f2bf(float x) {
    union { float f; unsigned u; } v; v.f = x;
    unsigned r = v.u + 0x7fffu + ((v.u >> 16) & 1u);   // RNE
    return (u16)(r >> 16);
}

__device__ inline void gload16(const u16* g, u16* l) {
    __builtin_amdgcn_global_load_lds(
        (const __attribute__((address_space(1))) unsigned int*)(const void*)g,
        (__attribute__((address_space(3))) unsigned int*)(void*)l, 16, 0, 0);
}

// ---------------------------------------------------------------------------
// fp32 -> bf16 conversion (vectorized, 8 elems/thread)
// ---------------------------------------------------------------------------
__global__ __launch_bounds__(256)
void cvt_qkv(const float* __restrict__ q, const float* __restrict__ k,
             const float* __restrict__ v,
             u16* __restrict__ oq, u16* __restrict__ ok, u16* __restrict__ ov)
{
    const float* s; u16* d;
    if (blockIdx.y == 0) { s = q; d = oq; }
    else if (blockIdx.y == 1) { s = k; d = ok; }
    else { s = v; d = ov; }
    const size_t i = ((size_t)blockIdx.x * 256 + threadIdx.x) * 8;
    const float4 a = *(const float4*)(s + i);
    const float4 c = *(const float4*)(s + i + 4);
    ushort8 r;
    r[0] = f2bf(a.x); r[1] = f2bf(a.y); r[2] = f2bf(a.z); r[3] = f2bf(a.w);
    r[4] = f2bf(c.x); r[5] = f2bf(c.y); r[6] = f2bf(c.z); r[7] = f2bf(c.w);
    *(ushort8*)(d + i) = r;
}

__global__ __launch_bounds__(256)
void cvt_w(const float* __restrict__ a, const float* __restrict__ b,
           const float* __restrict__ c, const float* __restrict__ e,
           u16* __restrict__ oa, u16* __restrict__ ob,
           u16* __restrict__ oc, u16* __restrict__ oe)
{
    const float* s; u16* d;
    if (blockIdx.y == 0) { s = a; d = oa; }
    else if (blockIdx.y == 1) { s = b; d = ob; }
    else if (blockIdx.y == 2) { s = c; d = oc; }
    else { s = e; d = oe; }
    const size_t i = ((size_t)blockIdx.x * 256 + threadIdx.x) * 8;
    const float4 x = *(const float4*)(s + i);
    const float4 y = *(const float4*)(s + i + 4);
    ushort8 r;
    r[0] = f2bf(x.x); r[1] = f2bf(x.y); r[2] = f2bf(x.z); r[3] = f2bf(x.w);
    r[4] = f2bf(y.x); r[5] = f2bf(y.y); r[6] = f2bf(y.z); r[7] = f2bf(y.w);
    *(ushort8*)(d + i) = r;
}

// ---------------------------------------------------------------------------
// V (BH,S,DH) -> Vt (BH,DH,S) transpose, bf16, LDS tiled
// ---------------------------------------------------------------------------
__global__ __launch_bounds__(256)
void transpose_v(const u16* __restrict__ Vp, u16* __restrict__ Vt)
{
    __shared__ __align__(16) u16 tile[64][72];
    const int t = threadIdx.x;
    const int s0 = blockIdx.x * 64;
    const int bh = blockIdx.y;
    const u16* src = Vp + ((size_t)bh * SS + s0) * DHH;
    const int r = t >> 2, d0 = (t & 3) * 16;
    *(ushort8*)&tile[r][d0]     = *(const ushort8*)(src + r * DHH + d0);
    *(ushort8*)&tile[r][d0 + 8] = *(const ushort8*)(src + r * DHH + d0 + 8);
    __syncthreads();
    const int d = t >> 2, sl = (t & 3) * 16;
    ushort8 o0, o1;
    #pragma unroll
    for (int j = 0; j < 8; ++j) o0[j] = tile[sl + j][d];
    #pragma unroll
    for (int j = 0; j < 8; ++j) o1[j] = tile[sl + 8 + j][d];
    u16* dst = Vt + ((size_t)bh * DHH + d) * SS + s0 + sl;
    *(ushort8*)dst       = o0;
    *(ushort8*)(dst + 8) = o1;
}

// ---------------------------------------------------------------------------
// bf16 NT GEMM: C = A (Mx1024) @ B^T, B row-major (1024x1024), 128x128 tile,
// BK=32, 4 waves (2x2), global_load_lds width-16 staging (m97 structure).
// OUT_MODE 0: fp32 row-major. OUT_MODE 1: bf16 head-split (B,H,S,DH).
// ---------------------------------------------------------------------------
template<int OUT_MODE>
__global__ __launch_bounds__(256)
void gemm_nt(const u16* __restrict__ A, const u16* __restrict__ B,
             void* __restrict__ Cv)
{
    __shared__ __align__(16) u16 As[128 * 32];
    __shared__ __align__(16) u16 Bs[128 * 32];
    const int t = threadIdx.x;
    const int w = t >> 6, l = t & 63;
    const int lm = l & 15, lg = l >> 4;
    const int m0 = blockIdx.y * 128, n0 = blockIdx.x * 128;
    const int wr = w >> 1, wc = w & 1;

    const u16* ga = A + (size_t)(m0 + w * 32 + (l >> 2)) * DD + (l & 3) * 8;
    const u16* gb = B + (size_t)(n0 + w * 32 + (l >> 2)) * DD + (l & 3) * 8;
    u16* lA0 = &As[w * 1024];
    u16* lA1 = &As[w * 1024 + 512];
    u16* lB0 = &Bs[w * 1024];
    u16* lB1 = &Bs[w * 1024 + 512];

    f32x4 acc[4][4];
    #pragma unroll
    for (int i = 0; i < 4; ++i)
        #pragma unroll
        for (int j = 0; j < 4; ++j)
            acc[i][j] = (f32x4){0.f, 0.f, 0.f, 0.f};

    for (int k0 = 0; k0 < DD; k0 += 32) {
        __syncthreads();
        gload16(ga + k0,           lA0);
        gload16(ga + k0 + 16 * DD, lA1);
        gload16(gb + k0,           lB0);
        gload16(gb + k0 + 16 * DD, lB1);
        __syncthreads();
        bf16x8 af[4], bfr[4];
        #pragma unroll
        for (int mi = 0; mi < 4; ++mi)
            af[mi] = *(const bf16x8*)&As[(wr * 64 + mi * 16 + lm) * 32 + lg * 8];
        #pragma unroll
        for (int ni = 0; ni < 4; ++ni)
            bfr[ni] = *(const bf16x8*)&Bs[(wc * 64 + ni * 16 + lm) * 32 + lg * 8];
        #pragma unroll
        for (int mi = 0; mi < 4; ++mi)
            #pragma unroll
            for (int ni = 0; ni < 4; ++ni)
                acc[mi][ni] = __builtin_amdgcn_mfma_f32_16x16x32_bf16(
                    af[mi], bfr[ni], acc[mi][ni], 0, 0, 0);
    }

    #pragma unroll
    for (int mi = 0; mi < 4; ++mi) {
        #pragma unroll
        for (int r = 0; r < 4; ++r) {
            const int m = m0 + wr * 64 + mi * 16 + lg * 4 + r;
            if (OUT_MODE == 0) {
                float* C = (float*)Cv;
                #pragma unroll
                for (int ni = 0; ni < 4; ++ni)
                    C[(size_t)m * DD + n0 + wc * 64 + ni * 16 + lm] = acc[mi][ni][r];
            } else {
                u16* C = (u16*)Cv;
                const int b = m >> 11, s = m & (SS - 1);
                #pragma unroll
                for (int ni = 0; ni < 4; ++ni) {
                    const int n = n0 + wc * 64 + ni * 16 + lm;
                    const int h = n >> 6, dh = n & 63;
                    C[(((size_t)b * HH + h) * SS + s) * DHH + dh] = f2bf(acc[mi][ni][r]);
                }
            }
        }
    }
}

// ---------------------------------------------------------------------------
// MFMA flash attention v2: 1 wave per block, 16 q-rows, loops over ALL 4
// batches (work per block = sum_b ceil(vlen_b/64) -> perfectly balanced grid,
// no drain tail). K/V fragments register-prefetched one tile ahead (issued
// after their last use; latency hidden under softmax+PV / next QK).
// No __syncthreads anywhere (wave-private P relayout buffer).
// ---------------------------------------------------------------------------
#define LOAD_K(bh_, c0_) do {                                                  \
    const u16* kb_ = Kp + ((size_t)(bh_) * SS + (c0_) + lm) * DHH + lg * 8;    \
    kf[0] = *(const bf16x8*)kb_;                                               \
    kf[1] = *(const bf16x8*)(kb_ + 32);                                        \
    kf[2] = *(const bf16x8*)(kb_ + 16 * DHH);                                  \
    kf[3] = *(const bf16x8*)(kb_ + 16 * DHH + 32);                             \
    kf[4] = *(const bf16x8*)(kb_ + 32 * DHH);                                  \
    kf[5] = *(const bf16x8*)(kb_ + 32 * DHH + 32);                             \
    kf[6] = *(const bf16x8*)(kb_ + 48 * DHH);                                  \
    kf[7] = *(const bf16x8*)(kb_ + 48 * DHH + 32);                             \
} while (0)

#define LOAD_V(bh_, c0_) do {                                                  \
    const u16* vb_ = Vt + ((size_t)(bh_) * DHH + lm) * SS + (c0_) + lg * 8;    \
    vf[0] = *(const bf16x8*)vb_;                                               \
    vf[1] = *(const bf16x8*)(vb_ + 32);                                        \
    vf[2] = *(const bf16x8*)(vb_ + 16 * SS);                                   \
    vf[3] = *(const bf16x8*)(vb_ + 16 * SS + 32);                              \
    vf[4] = *(const bf16x8*)(vb_ + 32 * SS);                                   \
    vf[5] = *(const bf16x8*)(vb_ + 32 * SS + 32);                              \
    vf[6] = *(const bf16x8*)(vb_ + 48 * SS);                                   \
    vf[7] = *(const bf16x8*)(vb_ + 48 * SS + 32);                              \
} while (0)

__global__ __launch_bounds__(64)
void flash_mfma2(const u16* __restrict__ Qp, const u16* __restrict__ Kp,
                 const u16* __restrict__ Vt, const int* __restrict__ vlens,
                 u16* __restrict__ AO)
{
    __shared__ __align__(16) u16 pw[16 * 72];
    const int l = threadIdx.x;
    const int lm = l & 15, lg = l >> 4;
    const int h = blockIdx.y;
    const int q0 = blockIdx.x * 16;

    int vl[4];
    #pragma unroll
    for (int b = 0; b < 4; ++b) vl[b] = vlens[b];

    bf16x8 kf[8], vf[8];
    LOAD_K(h, 0);        // (b=0, tile 0)
    LOAD_V(h, 0);

    for (int b = 0; b < 4; ++b) {
        const int bh = b * 16 + h;
        const int vlen = vl[b];
        const int ntb = (vlen + 63) >> 6;

        const u16* qb = Qp + ((size_t)bh * SS + q0 + lm) * DHH + lg * 8;
        const bf16x8 qf0 = *(const bf16x8*)qb;
        const bf16x8 qf1 = *(const bf16x8*)(qb + 32);

        f32x4 o[4];
        float m_r[4], l_r[4];
        #pragma unroll
        for (int r = 0; r < 4; ++r) { m_r[r] = -1e30f; l_r[r] = 0.f; }
        #pragma unroll
        for (int df = 0; df < 4; ++df) o[df] = (f32x4){0.f, 0.f, 0.f, 0.f};

        for (int tt = 0; tt < ntb; ++tt) {
            const int c0 = tt * 64;
            // --- QK^T on current K frags
            f32x4 s[4];
            #pragma unroll
            for (int cf = 0; cf < 4; ++cf) {
                f32x4 z = (f32x4){0.f, 0.f, 0.f, 0.f};
                z = __builtin_amdgcn_mfma_f32_16x16x32_bf16(qf0, kf[cf * 2],     z, 0, 0, 0);
                z = __builtin_amdgcn_mfma_f32_16x16x32_bf16(qf1, kf[cf * 2 + 1], z, 0, 0, 0);
                s[cf] = z;
            }
            // --- prefetch next tile's K (WAR-safe; hidden under softmax+PV)
            int bn = b, tn = tt + 1;
            if (tn == ntb) { bn = b + 1; tn = 0; }
            if (bn < 4) { const int nbh = bn * 16 + h, nc0 = tn * 64; LOAD_K(nbh, nc0); }

            // --- mask + online softmax
            const int rem = vlen - c0;   // >= 1
            #pragma unroll
            for (int cf = 0; cf < 4; ++cf) {
                const bool valid = (cf * 16 + lm) < rem;
                #pragma unroll
                for (int r = 0; r < 4; ++r)
                    s[cf][r] = valid ? s[cf][r] * 0.125f : -1e30f;
            }
            float vmax[4];
            #pragma unroll
            for (int r = 0; r < 4; ++r)
                vmax[r] = fmaxf(fmaxf(s[0][r], s[1][r]), fmaxf(s[2][r], s[3][r]));
            #pragma unroll
            for (int d = 1; d < 16; d <<= 1)
                #pragma unroll
                for (int r = 0; r < 4; ++r)
                    vmax[r] = fmaxf(vmax[r], __shfl_xor(vmax[r], d));
            float corr[4];
            #pragma unroll
            for (int r = 0; r < 4; ++r) {
                const float mn = fmaxf(m_r[r], vmax[r]);
                corr[r] = __expf(m_r[r] - mn);
                m_r[r] = mn;
            }
            float ps[4] = {0.f, 0.f, 0.f, 0.f};
            #pragma unroll
            for (int cf = 0; cf < 4; ++cf)
                #pragma unroll
                for (int r = 0; r < 4; ++r) {
                    const float p = __expf(s[cf][r] - m_r[r]);
                    s[cf][r] = p;
                    ps[r] += p;
                }
            #pragma unroll
            for (int d = 1; d < 16; d <<= 1)
                #pragma unroll
                for (int r = 0; r < 4; ++r)
                    ps[r] += __shfl_xor(ps[r], d);
            #pragma unroll
            for (int r = 0; r < 4; ++r)
                l_r[r] = l_r[r] * corr[r] + ps[r];
            #pragma unroll
            for (int df = 0; df < 4; ++df)
                #pragma unroll
                for (int r = 0; r < 4; ++r)
                    o[df][r] *= corr[r];

            // --- P (C/D layout) -> LDS -> A-operand layout, bf16
            #pragma unroll
            for (int cf = 0; cf < 4; ++cf)
                #pragma unroll
                for (int r = 0; r < 4; ++r)
                    pw[(lg * 4 + r) * 72 + cf * 16 + lm] = f2bf(s[cf][r]);
            asm volatile("s_waitcnt lgkmcnt(0)" ::: "memory");
            __builtin_amdgcn_sched_barrier(0);
            const bf16x8 pa0 = *(const bf16x8*)&pw[lm * 72 + lg * 8];
            const bf16x8 pa1 = *(const bf16x8*)&pw[lm * 72 + 32 + lg * 8];
            __builtin_amdgcn_sched_barrier(0);

            // --- PV on current V frags
            #pragma unroll
            for (int df = 0; df < 4; ++df) {
                o[df] = __builtin_amdgcn_mfma_f32_16x16x32_bf16(pa0, vf[df * 2],     o[df], 0, 0, 0);
                o[df] = __builtin_amdgcn_mfma_f32_16x16x32_bf16(pa1, vf[df * 2 + 1], o[df], 0, 0, 0);
            }
            // --- prefetch next tile's V (hidden under next QK+softmax)
            if (bn < 4) { const int nbh = bn * 16 + h, nc0 = tn * 64; LOAD_V(nbh, nc0); }
        }

        #pragma unroll
        for (int r = 0; r < 4; ++r) {
            const float inv = 1.f / l_r[r];
            const size_t rowbase = ((size_t)b * SS + q0 + lg * 4 + r) * DD + h * DHH;
            #pragma unroll
            for (int df = 0; df < 4; ++df)
                AO[rowbase + df * 16 + lm] = f2bf(o[df][r] * inv);
        }
    }
}

extern "C" void kernel_launch(void* const* d_in, const int* in_sizes, int n_in,
                              void* d_out, int out_size, void* d_ws, size_t ws_size,
                              hipStream_t stream) {
    const float* queries = (const float*)d_in[0];
    const float* keys    = (const float*)d_in[1];
    const float* values  = (const float*)d_in[2];
    const int*   vlens   = (const int*)d_in[3];
    const float* Wq      = (const float*)d_in[4];
    const float* Wk      = (const float*)d_in[5];
    const float* Wv      = (const float*)d_in[6];
    const float* Wo      = (const float*)d_in[7];

    u16* ws = (u16*)d_ws;
    const size_t NX = (size_t)BB * SS * DD;   // 8,388,608
    const size_t NW = (size_t)DD * DD;        // 1,048,576
    u16* Xq  = ws;
    u16* Xk  = Xq  + NX;
    u16* Xv  = Xk  + NX;
    u16* Wqb = Xv  + NX;
    u16* Wkb = Wqb + NW;
    u16* Wvb = Wkb + NW;
    u16* Wob = Wvb + NW;
    u16* Qp  = Wob + NW;
    u16* Kp  = Qp  + NX;
    u16* Vp  = Kp  + NX;
    u16* Vtb = Vp  + NX;
    u16* AO  = Xq;   // alias: Xq dead after the Q projection

    cvt_qkv<<<dim3(NX / 2048, 3), 256, 0, stream>>>(queries, keys, values, Xq, Xk, Xv);
    cvt_w<<<dim3(NW / 2048, 4), 256, 0, stream>>>(Wq, Wk, Wv, Wo, Wqb, Wkb, Wvb, Wob);

    const dim3 gg(DD / 128, (BB * SS) / 128);   // (8, 64)
    gemm_nt<1><<<gg, 256, 0, stream>>>(Xq, Wqb, Qp);
    gemm_nt<1><<<gg, 256, 0, stream>>>(Xk, Wkb, Kp);
    gemm_nt<1><<<gg, 256, 0, stream>>>(Xv, Wvb, Vp);

    transpose_v<<<dim3(SS / 64, NBH), 256, 0, stream>>>(Vp, Vtb);
    flash_mfma2<<<dim3(SS / 16, HH), 64, 0, stream>>>(Qp, Kp, Vtb, vlens, AO);

    gemm_nt<0><<<gg, 256, 0, stream>>>(AO, Wob, (float*)d_out);
}

// Round 4
// 398.433 us; speedup vs baseline: 6.1580x; 1.0033x over previous
//
#include <hip/hip_runtime.h>
#include <math.h>

#define BB 4
#define SS 2048
#define DD 1024
#define HH 16
#define DHH 64
#define NBH 64

typedef __attribute__((ext_vector_type(8))) short bf16x8;
typedef __attribute__((ext_vector_type(8))) unsigned short ushort8;
typedef __attribute__((ext_vector_type(4))) float f32x4;
typedef unsigned short u16;

__device__ inline u16 f2bf(float x) {
    union { float f; unsigned u; } v; v.f = x;
    unsigned r = v.u + 0x7fffu + ((v.u >> 16) & 1u);   // RNE
    return (u16)(r >> 16);
}

__device__ inline void gload16(const u16* g, u16* l) {
    __builtin_amdgcn_global_load_lds(
        (const __attribute__((address_space(1))) unsigned int*)(const void*)g,
        (__attribute__((address_space(3))) unsigned int*)(void*)l, 16, 0, 0);
}

// ---------------------------------------------------------------------------
// fp32 -> bf16 conversion (vectorized, 8 elems/thread)
// ---------------------------------------------------------------------------
__global__ __launch_bounds__(256)
void cvt_qkv(const float* __restrict__ q, const float* __restrict__ k,
             const float* __restrict__ v,
             u16* __restrict__ oq, u16* __restrict__ ok, u16* __restrict__ ov)
{
    const float* s; u16* d;
    if (blockIdx.y == 0) { s = q; d = oq; }
    else if (blockIdx.y == 1) { s = k; d = ok; }
    else { s = v; d = ov; }
    const size_t i = ((size_t)blockIdx.x * 256 + threadIdx.x) * 8;
    const float4 a = *(const float4*)(s + i);
    const float4 c = *(const float4*)(s + i + 4);
    ushort8 r;
    r[0] = f2bf(a.x); r[1] = f2bf(a.y); r[2] = f2bf(a.z); r[3] = f2bf(a.w);
    r[4] = f2bf(c.x); r[5] = f2bf(c.y); r[6] = f2bf(c.z); r[7] = f2bf(c.w);
    *(ushort8*)(d + i) = r;
}

__global__ __launch_bounds__(256)
void cvt_w(const float* __restrict__ a, const float* __restrict__ b,
           const float* __restrict__ c, const float* __restrict__ e,
           u16* __restrict__ oa, u16* __restrict__ ob,
           u16* __restrict__ oc, u16* __restrict__ oe)
{
    const float* s; u16* d;
    if (blockIdx.y == 0) { s = a; d = oa; }
    else if (blockIdx.y == 1) { s = b; d = ob; }
    else if (blockIdx.y == 2) { s = c; d = oc; }
    else { s = e; d = oe; }
    const size_t i = ((size_t)blockIdx.x * 256 + threadIdx.x) * 8;
    const float4 x = *(const float4*)(s + i);
    const float4 y = *(const float4*)(s + i + 4);
    ushort8 r;
    r[0] = f2bf(x.x); r[1] = f2bf(x.y); r[2] = f2bf(x.z); r[3] = f2bf(x.w);
    r[4] = f2bf(y.x); r[5] = f2bf(y.y); r[6] = f2bf(y.z); r[7] = f2bf(y.w);
    *(ushort8*)(d + i) = r;
}

// ---------------------------------------------------------------------------
// V (BH,S,DH) -> Vt (BH,DH,S) transpose, bf16, LDS tiled
// ---------------------------------------------------------------------------
__global__ __launch_bounds__(256)
void transpose_v(const u16* __restrict__ Vp, u16* __restrict__ Vt)
{
    __shared__ __align__(16) u16 tile[64][72];
    const int t = threadIdx.x;
    const int s0 = blockIdx.x * 64;
    const int bh = blockIdx.y;
    const u16* src = Vp + ((size_t)bh * SS + s0) * DHH;
    const int r = t >> 2, d0 = (t & 3) * 16;
    *(ushort8*)&tile[r][d0]     = *(const ushort8*)(src + r * DHH + d0);
    *(ushort8*)&tile[r][d0 + 8] = *(const ushort8*)(src + r * DHH + d0 + 8);
    __syncthreads();
    const int d = t >> 2, sl = (t & 3) * 16;
    ushort8 o0, o1;
    #pragma unroll
    for (int j = 0; j < 8; ++j) o0[j] = tile[sl + j][d];
    #pragma unroll
    for (int j = 0; j < 8; ++j) o1[j] = tile[sl + 8 + j][d];
    u16* dst = Vt + ((size_t)bh * DHH + d) * SS + s0 + sl;
    *(ushort8*)dst       = o0;
    *(ushort8*)(dst + 8) = o1;
}

// ---------------------------------------------------------------------------
// bf16 NT GEMM: C = A (Mx1024) @ B^T, B row-major (1024x1024), 128x128 tile,
// BK=32, 4 waves (2x2), global_load_lds width-16 staging (m97 structure).
// OUT_MODE 0: fp32 row-major. OUT_MODE 1: bf16 head-split (B,H,S,DH).
// ---------------------------------------------------------------------------
template<int OUT_MODE>
__global__ __launch_bounds__(256)
void gemm_nt(const u16* __restrict__ A, const u16* __restrict__ B,
             void* __restrict__ Cv)
{
    __shared__ __align__(16) u16 As[128 * 32];
    __shared__ __align__(16) u16 Bs[128 * 32];
    const int t = threadIdx.x;
    const int w = t >> 6, l = t & 63;
    const int lm = l & 15, lg = l >> 4;
    const int m0 = blockIdx.y * 128, n0 = blockIdx.x * 128;
    const int wr = w >> 1, wc = w & 1;

    const u16* ga = A + (size_t)(m0 + w * 32 + (l >> 2)) * DD + (l & 3) * 8;
    const u16* gb = B + (size_t)(n0 + w * 32 + (l >> 2)) * DD + (l & 3) * 8;
    u16* lA0 = &As[w * 1024];
    u16* lA1 = &As[w * 1024 + 512];
    u16* lB0 = &Bs[w * 1024];
    u16* lB1 = &Bs[w * 1024 + 512];

    f32x4 acc[4][4];
    #pragma unroll
    for (int i = 0; i < 4; ++i)
        #pragma unroll
        for (int j = 0; j < 4; ++j)
            acc[i][j] = (f32x4){0.f, 0.f, 0.f, 0.f};

    for (int k0 = 0; k0 < DD; k0 += 32) {
        __syncthreads();
        gload16(ga + k0,           lA0);
        gload16(ga + k0 + 16 * DD, lA1);
        gload16(gb + k0,           lB0);
        gload16(gb + k0 + 16 * DD, lB1);
        __syncthreads();
        bf16x8 af[4], bfr[4];
        #pragma unroll
        for (int mi = 0; mi < 4; ++mi)
            af[mi] = *(const bf16x8*)&As[(wr * 64 + mi * 16 + lm) * 32 + lg * 8];
        #pragma unroll
        for (int ni = 0; ni < 4; ++ni)
            bfr[ni] = *(const bf16x8*)&Bs[(wc * 64 + ni * 16 + lm) * 32 + lg * 8];
        #pragma unroll
        for (int mi = 0; mi < 4; ++mi)
            #pragma unroll
            for (int ni = 0; ni < 4; ++ni)
                acc[mi][ni] = __builtin_amdgcn_mfma_f32_16x16x32_bf16(
                    af[mi], bfr[ni], acc[mi][ni], 0, 0, 0);
    }

    #pragma unroll
    for (int mi = 0; mi < 4; ++mi) {
        #pragma unroll
        for (int r = 0; r < 4; ++r) {
            const int m = m0 + wr * 64 + mi * 16 + lg * 4 + r;
            if (OUT_MODE == 0) {
                float* C = (float*)Cv;
                #pragma unroll
                for (int ni = 0; ni < 4; ++ni)
                    C[(size_t)m * DD + n0 + wc * 64 + ni * 16 + lm] = acc[mi][ni][r];
            } else {
                u16* C = (u16*)Cv;
                const int b = m >> 11, s = m & (SS - 1);
                #pragma unroll
                for (int ni = 0; ni < 4; ++ni) {
                    const int n = n0 + wc * 64 + ni * 16 + lm;
                    const int h = n >> 6, dh = n & 63;
                    C[(((size_t)b * HH + h) * SS + s) * DHH + dh] = f2bf(acc[mi][ni][r]);
                }
            }
        }
    }
}

// ---------------------------------------------------------------------------
// MFMA flash attention v3. Swapped QK^T: S^T = mfma(A=K, B=Q) so each lane
// owns ONE q-row (q = lane&15); row softmax = in-lane reduce + 2 shfl_xor.
// exp2-folded scale, defer-max (THR=8), last-tile-only masking.
// P relayout: 8 cvt_pk_bf16 + 4 ds_write_b64 + 2 ds_read_b128 per tile.
// 4 independent waves/block (share K/V via L1), grid (S/64, H, B).
// K/V register-prefetched one tile ahead.
// ---------------------------------------------------------------------------
#define LOAD_K3(c0_) do {                                                      \
    const u16* kp_ = kb + ((size_t)(c0_) + lm) * DHH + lg * 8;                 \
    kf[0] = *(const bf16x8*)kp_;                                               \
    kf[1] = *(const bf16x8*)(kp_ + 32);                                        \
    kf[2] = *(const bf16x8*)(kp_ + 16 * DHH);                                  \
    kf[3] = *(const bf16x8*)(kp_ + 16 * DHH + 32);                             \
    kf[4] = *(const bf16x8*)(kp_ + 32 * DHH);                                  \
    kf[5] = *(const bf16x8*)(kp_ + 32 * DHH + 32);                             \
    kf[6] = *(const bf16x8*)(kp_ + 48 * DHH);                                  \
    kf[7] = *(const bf16x8*)(kp_ + 48 * DHH + 32);                             \
} while (0)

#define LOAD_V3(c0_) do {                                                      \
    const u16* vp_ = vb + (size_t)lm * SS + (c0_) + lg * 8;                    \
    vf[0] = *(const bf16x8*)vp_;                                               \
    vf[1] = *(const bf16x8*)(vp_ + 32);                                        \
    vf[2] = *(const bf16x8*)(vp_ + 16 * SS);                                   \
    vf[3] = *(const bf16x8*)(vp_ + 16 * SS + 32);                              \
    vf[4] = *(const bf16x8*)(vp_ + 32 * SS);                                   \
    vf[5] = *(const bf16x8*)(vp_ + 32 * SS + 32);                              \
    vf[6] = *(const bf16x8*)(vp_ + 48 * SS);                                   \
    vf[7] = *(const bf16x8*)(vp_ + 48 * SS + 32);                              \
} while (0)

__global__ __launch_bounds__(256)
void flash_mfma3(const u16* __restrict__ Qp, const u16* __restrict__ Kp,
                 const u16* __restrict__ Vt, const int* __restrict__ vlens,
                 u16* __restrict__ AO)
{
    __shared__ __align__(16) u16 pws[4][16 * 80];   // per-wave P buffer, stride 80
    const int t = threadIdx.x, w = t >> 6, l = t & 63;
    const int lm = l & 15, lg = l >> 4;
    const int h = blockIdx.y, b = blockIdx.z;
    const int bh = b * 16 + h;
    const int q0 = blockIdx.x * 64 + w * 16;
    const int vlen = vlens[b];
    const int ntb = (vlen + 63) >> 6;
    u16* pw = pws[w];

    const float SC = 0.18033688011112042f;   // 0.125 * log2(e)

    const u16* qb = Qp + ((size_t)bh * SS + q0 + lm) * DHH + lg * 8;
    const bf16x8 qf0 = *(const bf16x8*)qb;
    const bf16x8 qf1 = *(const bf16x8*)(qb + 32);

    const u16* kb = Kp + (size_t)bh * SS * DHH;
    const u16* vb = Vt + (size_t)bh * DHH * SS;

    bf16x8 kf[8], vf[8];
    LOAD_K3(0);
    LOAD_V3(0);

    f32x4 o[4];
    #pragma unroll
    for (int df = 0; df < 4; ++df) o[df] = (f32x4){0.f, 0.f, 0.f, 0.f};
    float m_run = -3e38f, l_run = 0.f;

    for (int tt = 0; tt < ntb; ++tt) {
        // --- QK^T swapped: z[cf] reg r = S^T[kpos = cf*16+lg*4+r][q = q0+lm]
        f32x4 z[4];
        #pragma unroll
        for (int cf = 0; cf < 4; ++cf) {
            f32x4 zz = (f32x4){0.f, 0.f, 0.f, 0.f};
            zz = __builtin_amdgcn_mfma_f32_16x16x32_bf16(kf[cf * 2],     qf0, zz, 0, 0, 0);
            zz = __builtin_amdgcn_mfma_f32_16x16x32_bf16(kf[cf * 2 + 1], qf1, zz, 0, 0, 0);
            z[cf] = zz;
        }
        // --- prefetch next tile's K (hidden under softmax+PV)
        if (tt + 1 < ntb) LOAD_K3((tt + 1) * 64);

        // --- mask (last tile only; wave-uniform branch)
        const int rem = vlen - tt * 64;
        if (rem < 64) {
            #pragma unroll
            for (int cf = 0; cf < 4; ++cf) {
                const int kb4 = cf * 16 + lg * 4;
                #pragma unroll
                for (int r = 0; r < 4; ++r)
                    if (kb4 + r >= rem) z[cf][r] = -3e38f;
            }
        }

        // --- row max: in-lane (16 vals) + cross-lg (2 shfl)
        float mx = fmaxf(fmaxf(z[0][0], z[0][1]), fmaxf(z[0][2], z[0][3]));
        #pragma unroll
        for (int cf = 1; cf < 4; ++cf)
            mx = fmaxf(mx, fmaxf(fmaxf(z[cf][0], z[cf][1]), fmaxf(z[cf][2], z[cf][3])));
        mx = fmaxf(mx, __shfl_xor(mx, 16));
        mx = fmaxf(mx, __shfl_xor(mx, 32));

        // --- defer-max: rescale only when raw max grows by > 64 (= 8 in ln space)
        float corr = 1.f;
        if (!__all(mx <= m_run + 64.0f)) {
            const float mold = m_run;
            m_run = fmaxf(m_run, mx);
            corr = exp2f((mold - m_run) * SC);
            float cr[4];
            #pragma unroll
            for (int r = 0; r < 4; ++r) cr[r] = __shfl(corr, lg * 4 + r);
            #pragma unroll
            for (int df = 0; df < 4; ++df)
                #pragma unroll
                for (int r = 0; r < 4; ++r) o[df][r] *= cr[r];
        }

        // --- p = exp2(z*SC - m*SC); in-lane sum + cross-lg
        const float tsc = m_run * SC;
        float tsum = 0.f;
        #pragma unroll
        for (int cf = 0; cf < 4; ++cf)
            #pragma unroll
            for (int r = 0; r < 4; ++r) {
                const float p = exp2f(__builtin_fmaf(z[cf][r], SC, -tsc));
                z[cf][r] = p;
                tsum += p;
            }
        tsum += __shfl_xor(tsum, 16);
        tsum += __shfl_xor(tsum, 32);
        l_run = l_run * corr + tsum;

        // --- P -> LDS (row q=lm, kpos ascending): 2 cvt_pk + 1 b64 write per cf
        #pragma unroll
        for (int cf = 0; cf < 4; ++cf) {
            unsigned pk0, pk1;
            asm("v_cvt_pk_bf16_f32 %0, %1, %2" : "=v"(pk0) : "v"(z[cf][0]), "v"(z[cf][1]));
            asm("v_cvt_pk_bf16_f32 %0, %1, %2" : "=v"(pk1) : "v"(z[cf][2]), "v"(z[cf][3]));
            uint2 u; u.x = pk0; u.y = pk1;
            *(uint2*)&pw[lm * 80 + cf * 16 + lg * 4] = u;
        }
        asm volatile("s_waitcnt lgkmcnt(0)" ::: "memory");
        __builtin_amdgcn_sched_barrier(0);
        const bf16x8 pa0 = *(const bf16x8*)&pw[lm * 80 + lg * 8];
        const bf16x8 pa1 = *(const bf16x8*)&pw[lm * 80 + 32 + lg * 8];
        __builtin_amdgcn_sched_barrier(0);

        // --- PV on current V frags
        #pragma unroll
        for (int df = 0; df < 4; ++df) {
            o[df] = __builtin_amdgcn_mfma_f32_16x16x32_bf16(pa0, vf[df * 2],     o[df], 0, 0, 0);
            o[df] = __builtin_amdgcn_mfma_f32_16x16x32_bf16(pa1, vf[df * 2 + 1], o[df], 0, 0, 0);
        }
        // --- prefetch next tile's V (hidden under next QK+softmax)
        if (tt + 1 < ntb) LOAD_V3((tt + 1) * 64);
    }

    // --- normalize + write (rows q = q0 + lg*4 + r; stats live at lane lm=row)
    const float inv = 1.f / l_run;
    float ir[4];
    #pragma unroll
    for (int r = 0; r < 4; ++r) ir[r] = __shfl(inv, lg * 4 + r);
    #pragma unroll
    for (int r = 0; r < 4; ++r) {
        const size_t rowbase = ((size_t)b * SS + q0 + lg * 4 + r) * DD + h * DHH;
        #pragma unroll
        for (int df = 0; df < 4; ++df)
            AO[rowbase + df * 16 + lm] = f2bf(o[df][r] * ir[r]);
    }
}

extern "C" void kernel_launch(void* const* d_in, const int* in_sizes, int n_in,
                              void* d_out, int out_size, void* d_ws, size_t ws_size,
                              hipStream_t stream) {
    const float* queries = (const float*)d_in[0];
    const float* keys    = (const float*)d_in[1];
    const float* values  = (const float*)d_in[2];
    const int*   vlens   = (const int*)d_in[3];
    const float* Wq      = (const float*)d_in[4];
    const float* Wk      = (const float*)d_in[5];
    const float* Wv      = (const float*)d_in[6];
    const float* Wo      = (const float*)d_in[7];

    u16* ws = (u16*)d_ws;
    const size_t NX = (size_t)BB * SS * DD;   // 8,388,608
    const size_t NW = (size_t)DD * DD;        // 1,048,576
    u16* Xq  = ws;
    u16* Xk  = Xq  + NX;
    u16* Xv  = Xk  + NX;
    u16* Wqb = Xv  + NX;
    u16* Wkb = Wqb + NW;
    u16* Wvb = Wkb + NW;
    u16* Wob = Wvb + NW;
    u16* Qp  = Wob + NW;
    u16* Kp  = Qp  + NX;
    u16* Vp  = Kp  + NX;
    u16* Vtb = Vp  + NX;
    u16* AO  = Xq;   // alias: Xq dead after the Q projection

    cvt_qkv<<<dim3(NX / 2048, 3), 256, 0, stream>>>(queries, keys, values, Xq, Xk, Xv);
    cvt_w<<<dim3(NW / 2048, 4), 256, 0, stream>>>(Wq, Wk, Wv, Wo, Wqb, Wkb, Wvb, Wob);

    const dim3 gg(DD / 128, (BB * SS) / 128);   // (8, 64)
    gemm_nt<1><<<gg, 256, 0, stream>>>(Xq, Wqb, Qp);
    gemm_nt<1><<<gg, 256, 0, stream>>>(Xk, Wkb, Kp);
    gemm_nt<1><<<gg, 256, 0, stream>>>(Xv, Wvb, Vp);

    transpose_v<<<dim3(SS / 64, NBH), 256, 0, stream>>>(Vp, Vtb);
    flash_mfma3<<<dim3(SS / 64, HH, BB), 256, 0, stream>>>(Qp, Kp, Vtb, vlens, AO);

    gemm_nt<0><<<gg, 256, 0, stream>>>(AO, Wob, (float*)d_out);
}

// Round 5
// 281.204 us; speedup vs baseline: 8.7252x; 1.4169x over previous
//
#include <hip/hip_runtime.h>
#include <math.h>

#define BB 4
#define SS 2048
#define DD 1024
#define HH 16
#define DHH 64
#define NBH 64

typedef __attribute__((ext_vector_type(8))) short bf16x8;
typedef __attribute__((ext_vector_type(8))) unsigned short ushort8;
typedef __attribute__((ext_vector_type(4))) float f32x4;
typedef __attribute__((ext_vector_type(16))) float f32x16;
typedef unsigned short u16;

__device__ inline u16 f2bf(float x) {
    union { float f; unsigned u; } v; v.f = x;
    unsigned r = v.u + 0x7fffu + ((v.u >> 16) & 1u);   // RNE
    return (u16)(r >> 16);
}

__device__ inline void gload16(const u16* g, u16* l) {
    __builtin_amdgcn_global_load_lds(
        (const __attribute__((address_space(1))) unsigned int*)(const void*)g,
        (__attribute__((address_space(3))) unsigned int*)(void*)l, 16, 0, 0);
}

// ---------------------------------------------------------------------------
// fp32 -> bf16 conversion (vectorized, 8 elems/thread)
// ---------------------------------------------------------------------------
__global__ __launch_bounds__(256)
void cvt_qkv(const float* __restrict__ q, const float* __restrict__ k,
             const float* __restrict__ v,
             u16* __restrict__ oq, u16* __restrict__ ok, u16* __restrict__ ov)
{
    const float* s; u16* d;
    if (blockIdx.y == 0) { s = q; d = oq; }
    else if (blockIdx.y == 1) { s = k; d = ok; }
    else { s = v; d = ov; }
    const size_t i = ((size_t)blockIdx.x * 256 + threadIdx.x) * 8;
    const float4 a = *(const float4*)(s + i);
    const float4 c = *(const float4*)(s + i + 4);
    ushort8 r;
    r[0] = f2bf(a.x); r[1] = f2bf(a.y); r[2] = f2bf(a.z); r[3] = f2bf(a.w);
    r[4] = f2bf(c.x); r[5] = f2bf(c.y); r[6] = f2bf(c.z); r[7] = f2bf(c.w);
    *(ushort8*)(d + i) = r;
}

__global__ __launch_bounds__(256)
void cvt_w(const float* __restrict__ a, const float* __restrict__ b,
           const float* __restrict__ c, const float* __restrict__ e,
           u16* __restrict__ oa, u16* __restrict__ ob,
           u16* __restrict__ oc, u16* __restrict__ oe)
{
    const float* s; u16* d;
    if (blockIdx.y == 0) { s = a; d = oa; }
    else if (blockIdx.y == 1) { s = b; d = ob; }
    else if (blockIdx.y == 2) { s = c; d = oc; }
    else { s = e; d = oe; }
    const size_t i = ((size_t)blockIdx.x * 256 + threadIdx.x) * 8;
    const float4 x = *(const float4*)(s + i);
    const float4 y = *(const float4*)(s + i + 4);
    ushort8 r;
    r[0] = f2bf(x.x); r[1] = f2bf(x.y); r[2] = f2bf(x.z); r[3] = f2bf(x.w);
    r[4] = f2bf(y.x); r[5] = f2bf(y.y); r[6] = f2bf(y.z); r[7] = f2bf(y.w);
    *(ushort8*)(d + i) = r;
}

// ---------------------------------------------------------------------------
// V (BH,S,DH) -> Vt (BH,DH,S) transpose, bf16, LDS tiled
// ---------------------------------------------------------------------------
__global__ __launch_bounds__(256)
void transpose_v(const u16* __restrict__ Vp, u16* __restrict__ Vt)
{
    __shared__ __align__(16) u16 tile[64][72];
    const int t = threadIdx.x;
    const int s0 = blockIdx.x * 64;
    const int bh = blockIdx.y;
    const u16* src = Vp + ((size_t)bh * SS + s0) * DHH;
    const int r = t >> 2, d0 = (t & 3) * 16;
    *(ushort8*)&tile[r][d0]     = *(const ushort8*)(src + r * DHH + d0);
    *(ushort8*)&tile[r][d0 + 8] = *(const ushort8*)(src + r * DHH + d0 + 8);
    __syncthreads();
    const int d = t >> 2, sl = (t & 3) * 16;
    ushort8 o0, o1;
    #pragma unroll
    for (int j = 0; j < 8; ++j) o0[j] = tile[sl + j][d];
    #pragma unroll
    for (int j = 0; j < 8; ++j) o1[j] = tile[sl + 8 + j][d];
    u16* dst = Vt + ((size_t)bh * DHH + d) * SS + s0 + sl;
    *(ushort8*)dst       = o0;
    *(ushort8*)(dst + 8) = o1;
}

// ---------------------------------------------------------------------------
// bf16 NT GEMM: C = A (Mx1024) @ B^T, B row-major (1024x1024), 128x128 tile,
// BK=32, 4 waves (2x2), global_load_lds width-16 staging (m97 structure).
// OUT_MODE 0: fp32 row-major. OUT_MODE 1: bf16 head-split (B,H,S,DH).
// ---------------------------------------------------------------------------
template<int OUT_MODE>
__global__ __launch_bounds__(256)
void gemm_nt(const u16* __restrict__ A, const u16* __restrict__ B,
             void* __restrict__ Cv)
{
    __shared__ __align__(16) u16 As[128 * 32];
    __shared__ __align__(16) u16 Bs[128 * 32];
    const int t = threadIdx.x;
    const int w = t >> 6, l = t & 63;
    const int lm = l & 15, lg = l >> 4;
    const int m0 = blockIdx.y * 128, n0 = blockIdx.x * 128;
    const int wr = w >> 1, wc = w & 1;

    const u16* ga = A + (size_t)(m0 + w * 32 + (l >> 2)) * DD + (l & 3) * 8;
    const u16* gb = B + (size_t)(n0 + w * 32 + (l >> 2)) * DD + (l & 3) * 8;
    u16* lA0 = &As[w * 1024];
    u16* lA1 = &As[w * 1024 + 512];
    u16* lB0 = &Bs[w * 1024];
    u16* lB1 = &Bs[w * 1024 + 512];

    f32x4 acc[4][4];
    #pragma unroll
    for (int i = 0; i < 4; ++i)
        #pragma unroll
        for (int j = 0; j < 4; ++j)
            acc[i][j] = (f32x4){0.f, 0.f, 0.f, 0.f};

    for (int k0 = 0; k0 < DD; k0 += 32) {
        __syncthreads();
        gload16(ga + k0,           lA0);
        gload16(ga + k0 + 16 * DD, lA1);
        gload16(gb + k0,           lB0);
        gload16(gb + k0 + 16 * DD, lB1);
        __syncthreads();
        bf16x8 af[4], bfr[4];
        #pragma unroll
        for (int mi = 0; mi < 4; ++mi)
            af[mi] = *(const bf16x8*)&As[(wr * 64 + mi * 16 + lm) * 32 + lg * 8];
        #pragma unroll
        for (int ni = 0; ni < 4; ++ni)
            bfr[ni] = *(const bf16x8*)&Bs[(wc * 64 + ni * 16 + lm) * 32 + lg * 8];
        #pragma unroll
        for (int mi = 0; mi < 4; ++mi)
            #pragma unroll
            for (int ni = 0; ni < 4; ++ni)
                acc[mi][ni] = __builtin_amdgcn_mfma_f32_16x16x32_bf16(
                    af[mi], bfr[ni], acc[mi][ni], 0, 0, 0);
    }

    #pragma unroll
    for (int mi = 0; mi < 4; ++mi) {
        #pragma unroll
        for (int r = 0; r < 4; ++r) {
            const int m = m0 + wr * 64 + mi * 16 + lg * 4 + r;
            if (OUT_MODE == 0) {
                float* C = (float*)Cv;
                #pragma unroll
                for (int ni = 0; ni < 4; ++ni)
                    C[(size_t)m * DD + n0 + wc * 64 + ni * 16 + lm] = acc[mi][ni][r];
            } else {
                u16* C = (u16*)Cv;
                const int b = m >> 11, s = m & (SS - 1);
                #pragma unroll
                for (int ni = 0; ni < 4; ++ni) {
                    const int n = n0 + wc * 64 + ni * 16 + lm;
                    const int h = n >> 6, dh = n & 63;
                    C[(((size_t)b * HH + h) * SS + s) * DHH + dh] = f2bf(acc[mi][ni][r]);
                }
            }
        }
    }
}

// ---------------------------------------------------------------------------
// MFMA flash attention v4: 32x32x16 MFMAs, double-swapped.
//   S^T = mfma(A=K, B=Q)    -> lane owns one q-row (q = lane&31) of scores
//   O^T = mfma(A=V^T, B=P^T)-> lane owns one q-row of output
// Fully in-register softmax: 2 shfl_xor(.,32) reductions + 4 exchange
// shuffles for the P^T B-fragments (16 cvt_pk). ZERO LDS, zero barriers.
// QBLK=32 rows/wave, KVBLK=32 per iteration, defer-max (THR=64 raw),
// last-tile-only masking, K/V frags prefetched post-consumption,
// s_setprio(1) around MFMA clusters.
// C/D layout (verified): col = lane&31, row = (reg&3)+8*(reg>>2)+4*(lane>>5).
// A/B k-mapping assumed: k = (lane>>5)*8 + j (consistent across QK and PV).
// ---------------------------------------------------------------------------
#define LOADK4(coff) do {                                                      \
    const u16* kp_ = kb + (size_t)(coff) * DHH;                                \
    kf[0] = *(const bf16x8*)kp_;                                               \
    kf[1] = *(const bf16x8*)(kp_ + 16);                                        \
    kf[2] = *(const bf16x8*)(kp_ + 32);                                        \
    kf[3] = *(const bf16x8*)(kp_ + 48);                                        \
} while (0)

#define LOADV4(coff) do {                                                      \
    const u16* vp_ = vb + (coff);                                              \
    va[0] = *(const bf16x8*)vp_;                                               \
    va[1] = *(const bf16x8*)(vp_ + 16);                                        \
    va[2] = *(const bf16x8*)(vp_ + (size_t)32 * SS);                           \
    va[3] = *(const bf16x8*)(vp_ + (size_t)32 * SS + 16);                      \
} while (0)

__global__ __launch_bounds__(256)
void flash_mfma4(const u16* __restrict__ Qp, const u16* __restrict__ Kp,
                 const u16* __restrict__ Vt, const int* __restrict__ vlens,
                 u16* __restrict__ AO)
{
    const int t = threadIdx.x, w = t >> 6, l = t & 63;
    const int l31 = l & 31, hi = l >> 5;
    const int h = blockIdx.y, b = blockIdx.z;
    const int bh = b * 16 + h;
    const int q0 = (blockIdx.x * 4 + w) * 32;
    const int vlen = vlens[b];
    const int ntb = (vlen + 31) >> 5;

    const float SC = 0.18033688011112042f;   // 0.125 * log2(e)

    // Q fragments (resident): B-operand of QK, k = dh
    const u16* qb = Qp + ((size_t)bh * SS + q0 + l31) * DHH + hi * 8;
    bf16x8 qv[4];
    qv[0] = *(const bf16x8*)qb;
    qv[1] = *(const bf16x8*)(qb + 16);
    qv[2] = *(const bf16x8*)(qb + 32);
    qv[3] = *(const bf16x8*)(qb + 48);

    const u16* kb = Kp + ((size_t)bh * SS + l31) * DHH + hi * 8;   // + kv*DHH
    const u16* vb = Vt + ((size_t)bh * DHH + l31) * SS + hi * 8;   // + dh*32*SS + kv

    bf16x8 kf[4], va[4];
    LOADK4(0);
    LOADV4(0);

    f32x16 ot0, ot1;
    #pragma unroll
    for (int r = 0; r < 16; ++r) { ot0[r] = 0.f; ot1[r] = 0.f; }
    float m_run = -3e38f, l_run = 0.f;

    for (int tt = 0; tt < ntb; ++tt) {
        const int c0 = tt * 32;
        // --- QK^T (S^T tile): z reg r = S[kv = c0+(r&3)+8(r>>2)+4hi][q = q0+l31]
        f32x16 z;
        #pragma unroll
        for (int r = 0; r < 16; ++r) z[r] = 0.f;
        __builtin_amdgcn_s_setprio(1);
        z = __builtin_amdgcn_mfma_f32_32x32x16_bf16(kf[0], qv[0], z, 0, 0, 0);
        z = __builtin_amdgcn_mfma_f32_32x32x16_bf16(kf[1], qv[1], z, 0, 0, 0);
        z = __builtin_amdgcn_mfma_f32_32x32x16_bf16(kf[2], qv[2], z, 0, 0, 0);
        z = __builtin_amdgcn_mfma_f32_32x32x16_bf16(kf[3], qv[3], z, 0, 0, 0);
        __builtin_amdgcn_s_setprio(0);
        // --- prefetch next K tile (hidden under softmax + PV)
        if (tt + 1 < ntb) LOADK4(c0 + 32);

        // --- mask (last tile only; wave-uniform branch)
        if (vlen - c0 < 32) {
            #pragma unroll
            for (int r = 0; r < 16; ++r) {
                const int kvl = (r & 3) + 8 * (r >> 2) + 4 * hi;
                if (c0 + kvl >= vlen) z[r] = -3e38f;
            }
        }

        // --- row max: 15 in-lane + 1 cross-half swap
        float mx = fmaxf(z[0], z[1]);
        #pragma unroll
        for (int r = 2; r < 16; ++r) mx = fmaxf(mx, z[r]);
        mx = fmaxf(mx, __shfl_xor(mx, 32));

        // --- defer-max: rescale only when raw max grows by > 64 (= 8 nats)
        float corr = 1.f;
        if (!__all(mx <= m_run + 64.0f)) {
            const float mold = m_run;
            m_run = fmaxf(m_run, mx);
            corr = exp2f((mold - m_run) * SC);
            #pragma unroll
            for (int r = 0; r < 16; ++r) { ot0[r] *= corr; ot1[r] *= corr; }
        }

        // --- p = exp2(z*SC - m*SC); in-lane sum + 1 swap
        const float msc = m_run * SC;
        float tsum = 0.f;
        #pragma unroll
        for (int r = 0; r < 16; ++r) {
            const float p = exp2f(__builtin_fmaf(z[r], SC, -msc));
            z[r] = p;
            tsum += p;
        }
        tsum += __shfl_xor(tsum, 32);
        l_run = l_run * corr + tsum;

        // --- pack P to bf16 pairs: group t' = regs 4t'..4t'+3
        unsigned u0, u1, u2, u3, u4, u5, u6, u7;
        asm("v_cvt_pk_bf16_f32 %0, %1, %2" : "=v"(u0) : "v"(z[0]),  "v"(z[1]));
        asm("v_cvt_pk_bf16_f32 %0, %1, %2" : "=v"(u1) : "v"(z[2]),  "v"(z[3]));
        asm("v_cvt_pk_bf16_f32 %0, %1, %2" : "=v"(u2) : "v"(z[4]),  "v"(z[5]));
        asm("v_cvt_pk_bf16_f32 %0, %1, %2" : "=v"(u3) : "v"(z[6]),  "v"(z[7]));
        asm("v_cvt_pk_bf16_f32 %0, %1, %2" : "=v"(u4) : "v"(z[8]),  "v"(z[9]));
        asm("v_cvt_pk_bf16_f32 %0, %1, %2" : "=v"(u5) : "v"(z[10]), "v"(z[11]));
        asm("v_cvt_pk_bf16_f32 %0, %1, %2" : "=v"(u6) : "v"(z[12]), "v"(z[13]));
        asm("v_cvt_pk_bf16_f32 %0, %1, %2" : "=v"(u7) : "v"(z[14]), "v"(z[15]));

        // --- exchange across lane-halves: hi=0 sends groups {1,3}, hi=1 sends {0,2}
        const unsigned s0 = __shfl_xor(hi ? u0 : u2, 32);
        const unsigned s1 = __shfl_xor(hi ? u1 : u3, 32);
        const unsigned s2 = __shfl_xor(hi ? u4 : u6, 32);
        const unsigned s3 = __shfl_xor(hi ? u5 : u7, 32);

        // --- assemble P^T B-fragments: frag m needs kv = 16m + 8*hi + j
        unsigned f0w[4], f1w[4];
        f0w[0] = hi ? s0 : u0;  f0w[1] = hi ? s1 : u1;
        f0w[2] = hi ? u2 : s0;  f0w[3] = hi ? u3 : s1;
        f1w[0] = hi ? s2 : u4;  f1w[1] = hi ? s3 : u5;
        f1w[2] = hi ? u6 : s2;  f1w[3] = hi ? u7 : s3;
        bf16x8 pb0, pb1;
        #pragma unroll
        for (int i = 0; i < 4; ++i) {
            ((unsigned*)&pb0)[i] = f0w[i];
            ((unsigned*)&pb1)[i] = f1w[i];
        }

        // --- PV: O^T += V^T * P^T
        __builtin_amdgcn_s_setprio(1);
        ot0 = __builtin_amdgcn_mfma_f32_32x32x16_bf16(va[0], pb0, ot0, 0, 0, 0);
        ot0 = __builtin_amdgcn_mfma_f32_32x32x16_bf16(va[1], pb1, ot0, 0, 0, 0);
        ot1 = __builtin_amdgcn_mfma_f32_32x32x16_bf16(va[2], pb0, ot1, 0, 0, 0);
        ot1 = __builtin_amdgcn_mfma_f32_32x32x16_bf16(va[3], pb1, ot1, 0, 0, 0);
        __builtin_amdgcn_s_setprio(0);
        // --- prefetch next V tile (hidden under next QK + softmax)
        if (tt + 1 < ntb) LOADV4(c0 + 32);
    }

    // --- normalize + write: lane owns q-row q0+l31; d = 32*dh + (r&3)+8(r>>2)+4hi
    const float inv = 1.f / l_run;
    u16* ob = AO + ((size_t)b * SS + q0 + l31) * DD + h * DHH + hi * 4;
    #pragma unroll
    for (int rq = 0; rq < 4; ++rq) {
        #pragma unroll
        for (int rp = 0; rp < 2; ++rp) {
            const int r = rq * 4 + rp * 2;
            unsigned w0, w1;
            asm("v_cvt_pk_bf16_f32 %0, %1, %2" : "=v"(w0)
                : "v"(ot0[r] * inv), "v"(ot0[r + 1] * inv));
            asm("v_cvt_pk_bf16_f32 %0, %1, %2" : "=v"(w1)
                : "v"(ot1[r] * inv), "v"(ot1[r + 1] * inv));
            *(unsigned*)(ob + rq * 8 + rp * 2)      = w0;
            *(unsigned*)(ob + 32 + rq * 8 + rp * 2) = w1;
        }
    }
}

extern "C" void kernel_launch(void* const* d_in, const int* in_sizes, int n_in,
                              void* d_out, int out_size, void* d_ws, size_t ws_size,
                              hipStream_t stream) {
    const float* queries = (const float*)d_in[0];
    const float* keys    = (const float*)d_in[1];
    const float* values  = (const float*)d_in[2];
    const int*   vlens   = (const int*)d_in[3];
    const float* Wq      = (const float*)d_in[4];
    const float* Wk      = (const float*)d_in[5];
    const float* Wv      = (const float*)d_in[6];
    const float* Wo      = (const float*)d_in[7];

    u16* ws = (u16*)d_ws;
    const size_t NX = (size_t)BB * SS * DD;   // 8,388,608
    const size_t NW = (size_t)DD * DD;        // 1,048,576
    u16* Xq  = ws;
    u16* Xk  = Xq  + NX;
    u16* Xv  = Xk  + NX;
    u16* Wqb = Xv  + NX;
    u16* Wkb = Wqb + NW;
    u16* Wvb = Wkb + NW;
    u16* Wob = Wvb + NW;
    u16* Qp  = Wob + NW;
    u16* Kp  = Qp  + NX;
    u16* Vp  = Kp  + NX;
    u16* Vtb = Vp  + NX;
    u16* AO  = Xq;   // alias: Xq dead after the Q projection

    cvt_qkv<<<dim3(NX / 2048, 3), 256, 0, stream>>>(queries, keys, values, Xq, Xk, Xv);
    cvt_w<<<dim3(NW / 2048, 4), 256, 0, stream>>>(Wq, Wk, Wv, Wo, Wqb, Wkb, Wvb, Wob);

    const dim3 gg(DD / 128, (BB * SS) / 128);   // (8, 64)
    gemm_nt<1><<<gg, 256, 0, stream>>>(Xq, Wqb, Qp);
    gemm_nt<1><<<gg, 256, 0, stream>>>(Xk, Wkb, Kp);
    gemm_nt<1><<<gg, 256, 0, stream>>>(Xv, Wvb, Vp);

    transpose_v<<<dim3(SS / 64, NBH), 256, 0, stream>>>(Vp, Vtb);
    flash_mfma4<<<dim3(SS / 128, HH, BB), 256, 0, stream>>>(Qp, Kp, Vtb, vlens, AO);

    gemm_nt<0><<<gg, 256, 0, stream>>>(AO, Wob, (float*)d_out);
}